// Round 3
// baseline (487.381 us; speedup 1.0000x reference)
//
#include <hip/hip_runtime.h>
#include <cstdint>

#define M_DIM 8192
#define K_DIM 4096
#define N_DIM 4096
#define NBLK 32      // K blocks
#define BLK  128     // quant block size along K

typedef int   v4i __attribute__((ext_vector_type(4)));
typedef float v4f __attribute__((ext_vector_type(4)));

__device__ __forceinline__ void gload_lds16(const void* g, void* l) {
  __builtin_amdgcn_global_load_lds(
      (const __attribute__((address_space(1))) void*)g,
      (__attribute__((address_space(3))) void*)l, 16, 0, 0);
}

// -------- Kernel 0: repack int32-materialized weights to int8 --------
// harness ABI: integer inputs arrive as int32. 4 int32 -> 1 packed int32.
__global__ __launch_bounds__(256) void pack_w(
    const int* __restrict__ w32, int* __restrict__ w8) {
  const size_t i = (size_t)blockIdx.x * 256 + threadIdx.x;
  const int4 v = ((const int4*)w32)[i];
  w8[i] = (v.x & 255) | ((v.y & 255) << 8) | ((v.z & 255) << 16) | ((v.w & 255) << 24);
}

// ---------------- Kernel 1: per-row dynamic int8 quantization ----------------
// one block (256 threads) per row of 4096 floats; each thread owns 16 elems.
__global__ __launch_bounds__(256) void quant_rows(
    const float* __restrict__ x, int8_t* __restrict__ xq, float* __restrict__ xs) {
  const int row = blockIdx.x;
  const int tid = threadIdx.x;
  const float4* xr = (const float4*)(x + (size_t)row * K_DIM);

  float4 v[4];
  float amax = 0.f;
#pragma unroll
  for (int i = 0; i < 4; ++i) {
    v[i] = xr[i * 256 + tid];  // coalesced: consecutive tids -> consecutive 16B
    amax = fmaxf(amax, fmaxf(fmaxf(fabsf(v[i].x), fabsf(v[i].y)),
                             fmaxf(fabsf(v[i].z), fabsf(v[i].w))));
  }
#pragma unroll
  for (int off = 32; off > 0; off >>= 1)
    amax = fmaxf(amax, __shfl_xor(amax, off, 64));

  __shared__ float red[4];
  if ((tid & 63) == 0) red[tid >> 6] = amax;
  __syncthreads();
  amax = fmaxf(fmaxf(red[0], red[1]), fmaxf(red[2], red[3]));
  amax = fmaxf(amax, 1e-6f);
  const float s = amax / 127.0f;   // matches ref: max(amax,eps)/127
  if (tid == 0) xs[row] = s;

  int* xqo = (int*)(xq + (size_t)row * K_DIM);
#pragma unroll
  for (int i = 0; i < 4; ++i) {
    // exact IEEE div + rintf (round-half-even) matches np.round(x / x_scale)
    int q0 = (int)fminf(fmaxf(rintf(v[i].x / s), -128.f), 127.f);
    int q1 = (int)fminf(fmaxf(rintf(v[i].y / s), -128.f), 127.f);
    int q2 = (int)fminf(fmaxf(rintf(v[i].z / s), -128.f), 127.f);
    int q3 = (int)fminf(fmaxf(rintf(v[i].w / s), -128.f), 127.f);
    xqo[i * 256 + tid] =
        (q0 & 255) | ((q1 & 255) << 8) | ((q2 & 255) << 16) | ((q3 & 255) << 24);
  }
}

// ---------------- Kernel 2: int8 block-scaled GEMM -----------------------
// 128x128 output tile per block, 256 threads (4 waves, 2x2), each wave a
// 64x64 region as 4x4 tiles of mfma_i32_16x16x64_i8. Per 128-K-block:
// 32 MFMAs into int32 acc, then facc += ws[b,n] * (float)iacc.
__global__ __launch_bounds__(256) void gemm_q8(
    const int8_t* __restrict__ xq, const int8_t* __restrict__ wq,
    const float* __restrict__ wscale, const float* __restrict__ xs,
    const float* __restrict__ bias, float* __restrict__ out) {
  __shared__ int8_t lA[128 * 128];  // 16 KB, rows = m, 8 chunks of 16B, XOR-swizzled
  __shared__ int8_t lB[128 * 128];  // rows = n

  const int tid = threadIdx.x;
  const int m0 = blockIdx.x * 128;
  const int n0 = blockIdx.y * 128;

  // staging: 16 KB per tile = 4 rounds of (256 threads x 16B).
  // round p: thread t -> row (t>>3)+32p, LDS offset t*16 + p*4096
  // (lane-contiguous, required by global_load_lds). gather the swizzled
  // source chunk so chunk c of row r lives at slot c ^ (r&7);
  // (r+32)&7 == r&7 so the chunk index is round-invariant.
  const int srow   = tid >> 3;
  const int schunk = (tid & 7) ^ (srow & 7);
  const int8_t* ga = xq + (size_t)(m0 + srow) * K_DIM + schunk * 16;
  const int8_t* gb = wq + (size_t)(n0 + srow) * K_DIM + schunk * 16;
  int8_t* la_dst = lA + tid * 16;
  int8_t* lb_dst = lB + tid * 16;

  const int lane = tid & 63;
  const int wv = tid >> 6;
  const int wm = (wv & 1) << 6;   // wave row offset in tile
  const int wn = (wv >> 1) << 6;  // wave col offset in tile
  const int lr = lane & 15;       // A row / B row(n) / C col within 16-tile
  const int lq = lane >> 4;       // quad

  // fragment LDS byte offsets: row*128 + (swizzled chunk)*16
  // frag k-range for half h: bytes k = h*64 + lq*16 .. +16 -> chunk h*4+lq
  int a_off[4][2], b_off[4][2];
#pragma unroll
  for (int i = 0; i < 4; ++i) {
#pragma unroll
    for (int h = 0; h < 2; ++h) {
      const int ch = (h << 2) | lq;
      const int rowA = wm + i * 16 + lr;
      const int rowB = wn + i * 16 + lr;
      a_off[i][h] = rowA * 128 + ((ch ^ (rowA & 7)) << 4);
      b_off[i][h] = rowB * 128 + ((ch ^ (rowB & 7)) << 4);
    }
  }

  v4f facc[4][4];
#pragma unroll
  for (int i = 0; i < 4; ++i)
#pragma unroll
    for (int j = 0; j < 4; ++j) facc[i][j] = {0.f, 0.f, 0.f, 0.f};

  const float* wsp = wscale + n0 + wn;  // wscale[b*N + n]

  for (int kb = 0; kb < NBLK; ++kb) {
    __syncthreads();
#pragma unroll
    for (int p = 0; p < 4; ++p) {
      gload_lds16(ga + (size_t)p * 32 * K_DIM, la_dst + p * 4096);
      gload_lds16(gb + (size_t)p * 32 * K_DIM, lb_dst + p * 4096);
    }
    ga += BLK;
    gb += BLK;
    __syncthreads();

    v4i iacc[4][4];
#pragma unroll
    for (int i = 0; i < 4; ++i)
#pragma unroll
      for (int j = 0; j < 4; ++j) iacc[i][j] = {0, 0, 0, 0};

#pragma unroll
    for (int h = 0; h < 2; ++h) {
      v4i af[4], bf[4];
#pragma unroll
      for (int i = 0; i < 4; ++i) af[i] = *(const v4i*)(lA + a_off[i][h]);
#pragma unroll
      for (int j = 0; j < 4; ++j) bf[j] = *(const v4i*)(lB + b_off[j][h]);
#pragma unroll
      for (int i = 0; i < 4; ++i)
#pragma unroll
        for (int j = 0; j < 4; ++j)
          iacc[i][j] = __builtin_amdgcn_mfma_i32_16x16x64_i8(af[i], bf[j],
                                                             iacc[i][j], 0, 0, 0);
    }

    const float* wsk = wsp + kb * N_DIM;
#pragma unroll
    for (int j = 0; j < 4; ++j) {
      const float wsv = wsk[j * 16 + lr];  // ws for this lane's output column
#pragma unroll
      for (int i = 0; i < 4; ++i)
#pragma unroll
        for (int r = 0; r < 4; ++r)
          facc[i][j][r] += wsv * (float)iacc[i][j][r];
    }
  }

  // epilogue: out[m,n] = facc * xs[m] + bias[n]
  float bv[4];
#pragma unroll
  for (int j = 0; j < 4; ++j) bv[j] = bias[n0 + wn + j * 16 + lr];
#pragma unroll
  for (int i = 0; i < 4; ++i) {
    const int mb = m0 + wm + i * 16 + (lq << 2);
#pragma unroll
    for (int r = 0; r < 4; ++r) {
      const float sc = xs[mb + r];
      float* op = out + (size_t)(mb + r) * N_DIM + n0 + wn + lr;
#pragma unroll
      for (int j = 0; j < 4; ++j) op[j * 16] = facc[i][j][r] * sc + bv[j];
    }
  }
}

extern "C" void kernel_launch(void* const* d_in, const int* in_sizes, int n_in,
                              void* d_out, int out_size, void* d_ws, size_t ws_size,
                              hipStream_t stream) {
  const float* x      = (const float*)d_in[0];
  const int*   w32    = (const int*)d_in[1];    // harness ABI: int8 ref -> int32 buffer
  const float* wscale = (const float*)d_in[2];
  const float* bias   = (const float*)d_in[3];
  float* out = (float*)d_out;

  // workspace layout: xq [33.5 MB] | wq8 [16.8 MB] | xs [32 KB]
  int8_t* xq  = (int8_t*)d_ws;
  int8_t* wq8 = (int8_t*)d_ws + (size_t)M_DIM * K_DIM;
  float*  xs  = (float*)((char*)d_ws + (size_t)M_DIM * K_DIM + (size_t)N_DIM * K_DIM);

  pack_w<<<(N_DIM * (size_t)K_DIM / 4 + 255) / 256, 256, 0, stream>>>(w32, (int*)wq8);
  quant_rows<<<M_DIM, 256, 0, stream>>>(x, xq, xs);
  dim3 grid(M_DIM / 128, N_DIM / 128);
  gemm_q8<<<grid, 256, 0, stream>>>(xq, wq8, wscale, xs, bias, out);
}

// Round 4
// 465.238 us; speedup vs baseline: 1.0476x; 1.0476x over previous
//
#include <hip/hip_runtime.h>
#include <cstdint>

#define M_DIM 8192
#define K_DIM 4096
#define N_DIM 4096
#define NBLK 32      // K blocks
#define BLK  128     // quant block size along K

typedef int   v4i __attribute__((ext_vector_type(4)));
typedef float v4f __attribute__((ext_vector_type(4)));

__device__ __forceinline__ void gload_lds16(const void* g, void* l) {
  __builtin_amdgcn_global_load_lds(
      (const __attribute__((address_space(1))) void*)g,
      (__attribute__((address_space(3))) void*)l, 16, 0, 0);
}

// -------- Kernel 0: repack int32-materialized weights to int8 --------
// harness ABI: integer inputs arrive as int32. 4 int32 -> 1 packed int32.
__global__ __launch_bounds__(256) void pack_w(
    const int* __restrict__ w32, int* __restrict__ w8) {
  const size_t i = (size_t)blockIdx.x * 256 + threadIdx.x;
  const int4 v = ((const int4*)w32)[i];
  w8[i] = (v.x & 255) | ((v.y & 255) << 8) | ((v.z & 255) << 16) | ((v.w & 255) << 24);
}

// ---------------- Kernel 1: per-row dynamic int8 quantization ----------------
// one block (256 threads) per row of 4096 floats; each thread owns 16 elems.
__global__ __launch_bounds__(256) void quant_rows(
    const float* __restrict__ x, int8_t* __restrict__ xq, float* __restrict__ xs) {
  const int row = blockIdx.x;
  const int tid = threadIdx.x;
  const float4* xr = (const float4*)(x + (size_t)row * K_DIM);

  float4 v[4];
  float amax = 0.f;
#pragma unroll
  for (int i = 0; i < 4; ++i) {
    v[i] = xr[i * 256 + tid];  // coalesced: consecutive tids -> consecutive 16B
    amax = fmaxf(amax, fmaxf(fmaxf(fabsf(v[i].x), fabsf(v[i].y)),
                             fmaxf(fabsf(v[i].z), fabsf(v[i].w))));
  }
#pragma unroll
  for (int off = 32; off > 0; off >>= 1)
    amax = fmaxf(amax, __shfl_xor(amax, off, 64));

  __shared__ float red[4];
  if ((tid & 63) == 0) red[tid >> 6] = amax;
  __syncthreads();
  amax = fmaxf(fmaxf(red[0], red[1]), fmaxf(red[2], red[3]));
  amax = fmaxf(amax, 1e-6f);
  const float s   = amax / 127.0f;   // matches ref: max(amax,eps)/127
  const float inv = 127.0f / amax;   // mul-by-reciprocal: worst-case flip = 0.06 abs, safe
  if (tid == 0) xs[row] = s;

  int* xqo = (int*)(xq + (size_t)row * K_DIM);
#pragma unroll
  for (int i = 0; i < 4; ++i) {
    int q0 = (int)fminf(fmaxf(rintf(v[i].x * inv), -128.f), 127.f);
    int q1 = (int)fminf(fmaxf(rintf(v[i].y * inv), -128.f), 127.f);
    int q2 = (int)fminf(fmaxf(rintf(v[i].z * inv), -128.f), 127.f);
    int q3 = (int)fminf(fmaxf(rintf(v[i].w * inv), -128.f), 127.f);
    xqo[i * 256 + tid] =
        (q0 & 255) | ((q1 & 255) << 8) | ((q2 & 255) << 16) | ((q3 & 255) << 24);
  }
}

// ---------------- Kernel 2: int8 block-scaled GEMM -----------------------
// 128x128 tile per block, 512 threads = 8 waves in 4(m) x 2(n); each wave a
// 32x64 region as 2x4 tiles of mfma_i32_16x16x64_i8. j-sequential dequant:
// only 8 int acc regs live at a time -> ~90 regs/wave -> 4+ waves/SIMD.
__global__ __launch_bounds__(512) void gemm_q8(
    const int8_t* __restrict__ xq, const int8_t* __restrict__ wq,
    const float* __restrict__ wscale, const float* __restrict__ xs,
    const float* __restrict__ bias, float* __restrict__ out) {
  __shared__ int8_t lA[128 * 128];  // 16 KB, rows = m, 8 chunks of 16B, XOR-swizzled
  __shared__ int8_t lB[128 * 128];  // rows = n

  const int tid = threadIdx.x;
  const int m0 = blockIdx.x * 128;
  const int n0 = blockIdx.y * 128;

  // staging: 16 KB per tile = 2 rounds of (512 threads x 16B).
  // round p: thread t -> row (t>>3)+64p, LDS offset t*16 + p*8192
  // (lane-contiguous, required by global_load_lds). gather the swizzled
  // source chunk so chunk c of row r lives at slot c ^ (r&7);
  // (r+64)&7 == r&7 so the chunk index is round-invariant.
  const int srow   = tid >> 3;
  const int schunk = (tid & 7) ^ (srow & 7);
  const int8_t* ga = xq + (size_t)(m0 + srow) * K_DIM + schunk * 16;
  const int8_t* gb = wq + (size_t)(n0 + srow) * K_DIM + schunk * 16;
  int8_t* la_dst = lA + tid * 16;
  int8_t* lb_dst = lB + tid * 16;

  const int lane = tid & 63;
  const int wv = tid >> 6;
  const int wm = (wv & 3) << 5;   // wave m-offset: 0/32/64/96
  const int wn = (wv >> 2) << 6;  // wave n-offset: 0/64
  const int lr = lane & 15;       // A row / B row(n) / C col within 16-tile
  const int lq = lane >> 4;       // quad

  // fragment LDS byte offsets: row*128 + (swizzled chunk)*16
  // frag k-range for half h: bytes k = h*64 + lq*16 -> chunk h*4+lq
  int a_off[2][2], b_off[4][2];
#pragma unroll
  for (int h = 0; h < 2; ++h) {
    const int ch = (h << 2) | lq;
#pragma unroll
    for (int i = 0; i < 2; ++i) {
      const int rowA = wm + i * 16 + lr;
      a_off[i][h] = rowA * 128 + ((ch ^ (rowA & 7)) << 4);
    }
#pragma unroll
    for (int j = 0; j < 4; ++j) {
      const int rowB = wn + j * 16 + lr;
      b_off[j][h] = rowB * 128 + ((ch ^ (rowB & 7)) << 4);
    }
  }

  v4f facc[2][4];
#pragma unroll
  for (int i = 0; i < 2; ++i)
#pragma unroll
    for (int j = 0; j < 4; ++j) facc[i][j] = {0.f, 0.f, 0.f, 0.f};

  const float* wsp = wscale + n0 + wn + lr;  // wscale[b*N + n], n = +j*16

  for (int kb = 0; kb < NBLK; ++kb) {
    // prefetch this block's 4 column scales above the barrier (latency slack)
    float wsv[4];
#pragma unroll
    for (int j = 0; j < 4; ++j) wsv[j] = wsp[(size_t)kb * N_DIM + j * 16];

    __syncthreads();
#pragma unroll
    for (int p = 0; p < 2; ++p) {
      gload_lds16(ga + (size_t)p * 64 * K_DIM, la_dst + p * 8192);
      gload_lds16(gb + (size_t)p * 64 * K_DIM, lb_dst + p * 8192);
    }
    ga += BLK;
    gb += BLK;
    __syncthreads();

    v4i af[2][2];
#pragma unroll
    for (int i = 0; i < 2; ++i)
#pragma unroll
      for (int h = 0; h < 2; ++h) af[i][h] = *(const v4i*)(lA + a_off[i][h]);

#pragma unroll
    for (int j = 0; j < 4; ++j) {
      const v4i b0 = *(const v4i*)(lB + b_off[j][0]);
      const v4i b1 = *(const v4i*)(lB + b_off[j][1]);
      v4i i0 = {0, 0, 0, 0}, i1 = {0, 0, 0, 0};
      i0 = __builtin_amdgcn_mfma_i32_16x16x64_i8(af[0][0], b0, i0, 0, 0, 0);
      i1 = __builtin_amdgcn_mfma_i32_16x16x64_i8(af[1][0], b0, i1, 0, 0, 0);
      i0 = __builtin_amdgcn_mfma_i32_16x16x64_i8(af[0][1], b1, i0, 0, 0, 0);
      i1 = __builtin_amdgcn_mfma_i32_16x16x64_i8(af[1][1], b1, i1, 0, 0, 0);
#pragma unroll
      for (int r = 0; r < 4; ++r) {
        facc[0][j][r] += wsv[j] * (float)i0[r];
        facc[1][j][r] += wsv[j] * (float)i1[r];
      }
    }
  }

  // epilogue: out[m,n] = facc * xs[m] + bias[n]
  float bv[4];
#pragma unroll
  for (int j = 0; j < 4; ++j) bv[j] = bias[n0 + wn + j * 16 + lr];
#pragma unroll
  for (int i = 0; i < 2; ++i) {
    const int mb = m0 + wm + i * 16 + (lq << 2);
#pragma unroll
    for (int r = 0; r < 4; ++r) {
      const float sc = xs[mb + r];
      float* op = out + (size_t)(mb + r) * N_DIM + n0 + wn + lr;
#pragma unroll
      for (int j = 0; j < 4; ++j) op[j * 16] = facc[i][j][r] * sc + bv[j];
    }
  }
}

extern "C" void kernel_launch(void* const* d_in, const int* in_sizes, int n_in,
                              void* d_out, int out_size, void* d_ws, size_t ws_size,
                              hipStream_t stream) {
  const float* x      = (const float*)d_in[0];
  const int*   w32    = (const int*)d_in[1];    // harness ABI: int8 ref -> int32 buffer
  const float* wscale = (const float*)d_in[2];
  const float* bias   = (const float*)d_in[3];
  float* out = (float*)d_out;

  // workspace layout: xq [33.5 MB] | wq8 [16.8 MB] | xs [32 KB]
  int8_t* xq  = (int8_t*)d_ws;
  int8_t* wq8 = (int8_t*)d_ws + (size_t)M_DIM * K_DIM;
  float*  xs  = (float*)((char*)d_ws + (size_t)M_DIM * K_DIM + (size_t)N_DIM * K_DIM);

  pack_w<<<(N_DIM * (size_t)K_DIM / 4 + 255) / 256, 256, 0, stream>>>(w32, (int*)wq8);
  quant_rows<<<M_DIM, 256, 0, stream>>>(x, xq, xs);
  dim3 grid(M_DIM / 128, N_DIM / 128);
  gemm_q8<<<grid, 512, 0, stream>>>(xq, wq8, wscale, xs, bias, out);
}

// Round 5
// 461.649 us; speedup vs baseline: 1.0557x; 1.0078x over previous
//
#include <hip/hip_runtime.h>
#include <cstdint>

#define M_DIM 8192
#define K_DIM 4096
#define N_DIM 4096
#define NBLK 32      // K blocks
#define BLK  128     // quant block size along K

typedef int   v4i __attribute__((ext_vector_type(4)));
typedef float v4f __attribute__((ext_vector_type(4)));

__device__ __forceinline__ void gload_lds16(const void* g, void* l) {
  __builtin_amdgcn_global_load_lds(
      (const __attribute__((address_space(1))) void*)g,
      (__attribute__((address_space(3))) void*)l, 16, 0, 0);
}

// -------- Kernel 0: repack int32-materialized weights to int8 --------
// harness ABI: integer inputs arrive as int32. 4 int32 -> 1 packed int32.
__global__ __launch_bounds__(256) void pack_w(
    const int* __restrict__ w32, int* __restrict__ w8) {
  const size_t i = (size_t)blockIdx.x * 256 + threadIdx.x;
  const int4 v = ((const int4*)w32)[i];
  w8[i] = (v.x & 255) | ((v.y & 255) << 8) | ((v.z & 255) << 16) | ((v.w & 255) << 24);
}

// ---------------- Kernel 1: per-row dynamic int8 quantization ----------------
// one block (256 threads) per row of 4096 floats; each thread owns 16 elems.
__global__ __launch_bounds__(256) void quant_rows(
    const float* __restrict__ x, int8_t* __restrict__ xq, float* __restrict__ xs) {
  const int row = blockIdx.x;
  const int tid = threadIdx.x;
  const float4* xr = (const float4*)(x + (size_t)row * K_DIM);

  float4 v[4];
  float amax = 0.f;
#pragma unroll
  for (int i = 0; i < 4; ++i) {
    v[i] = xr[i * 256 + tid];  // coalesced: consecutive tids -> consecutive 16B
    amax = fmaxf(amax, fmaxf(fmaxf(fabsf(v[i].x), fabsf(v[i].y)),
                             fmaxf(fabsf(v[i].z), fabsf(v[i].w))));
  }
#pragma unroll
  for (int off = 32; off > 0; off >>= 1)
    amax = fmaxf(amax, __shfl_xor(amax, off, 64));

  __shared__ float red[4];
  if ((tid & 63) == 0) red[tid >> 6] = amax;
  __syncthreads();
  amax = fmaxf(fmaxf(red[0], red[1]), fmaxf(red[2], red[3]));
  amax = fmaxf(amax, 1e-6f);
  const float s   = amax / 127.0f;   // matches ref: max(amax,eps)/127
  const float inv = 127.0f / amax;   // mul-by-reciprocal: worst-case flip = 0.06 abs, safe
  if (tid == 0) xs[row] = s;

  int* xqo = (int*)(xq + (size_t)row * K_DIM);
#pragma unroll
  for (int i = 0; i < 4; ++i) {
    int q0 = (int)fminf(fmaxf(rintf(v[i].x * inv), -128.f), 127.f);
    int q1 = (int)fminf(fmaxf(rintf(v[i].y * inv), -128.f), 127.f);
    int q2 = (int)fminf(fmaxf(rintf(v[i].z * inv), -128.f), 127.f);
    int q3 = (int)fminf(fmaxf(rintf(v[i].w * inv), -128.f), 127.f);
    xqo[i * 256 + tid] =
        (q0 & 255) | ((q1 & 255) << 8) | ((q2 & 255) << 16) | ((q3 & 255) << 24);
  }
}

// ---------------- Kernel 2: int8 block-scaled GEMM -----------------------
// 128x128 tile per block, 256 threads = 4 waves in a 2x2 grid; each wave a
// 64x64 region as 4x4 tiles of mfma_i32_16x16x64_i8.
// Wave-grid is square to minimize LDS read amplification: 16 KB/wave-iter
// (4 B per output elem per K-block) vs 24 KB for a 4x2 grid — LDS pipe was
// the R4 co-bottleneck (96 KB/block-iter = 120 us floor > 70 us MFMA floor).
// ~150 VGPR -> 3 waves/SIMD -> 3 independent blocks/CU (m97 overlap regime).
__global__ __launch_bounds__(256) void gemm_q8(
    const int8_t* __restrict__ xq, const int8_t* __restrict__ wq,
    const float* __restrict__ wscale, const float* __restrict__ xs,
    const float* __restrict__ bias, float* __restrict__ out) {
  __shared__ int8_t lA[128 * 128];  // 16 KB, rows = m, 8 chunks of 16B, XOR-swizzled
  __shared__ int8_t lB[128 * 128];  // rows = n

  const int tid = threadIdx.x;
  const int m0 = blockIdx.x * 128;
  const int n0 = blockIdx.y * 128;

  // staging: 16 KB per tile = 4 rounds of (256 threads x 16B).
  // round p: thread t -> row (t>>3)+32p, LDS offset t*16 + p*4096
  // (lane-contiguous, required by global_load_lds). gather the swizzled
  // source chunk so chunk c of row r lives at slot c ^ (r&7);
  // (r+32)&7 == r&7 so the chunk index is round-invariant.
  const int srow   = tid >> 3;
  const int schunk = (tid & 7) ^ (srow & 7);
  const int8_t* ga = xq + (size_t)(m0 + srow) * K_DIM + schunk * 16;
  const int8_t* gb = wq + (size_t)(n0 + srow) * K_DIM + schunk * 16;
  int8_t* la_dst = lA + tid * 16;
  int8_t* lb_dst = lB + tid * 16;

  const int lane = tid & 63;
  const int wv = tid >> 6;
  const int wm = (wv & 1) << 6;   // wave m-offset: 0/64
  const int wn = (wv >> 1) << 6;  // wave n-offset: 0/64
  const int lr = lane & 15;       // A row / B row(n) / C col within 16-tile
  const int lq = lane >> 4;       // quad

  // fragment LDS byte offsets: row*128 + (swizzled chunk)*16
  // frag k-range for half h: bytes k = h*64 + lq*16 -> chunk h*4+lq
  int a_off[4][2], b_off[4][2];
#pragma unroll
  for (int h = 0; h < 2; ++h) {
    const int ch = (h << 2) | lq;
#pragma unroll
    for (int i = 0; i < 4; ++i) {
      const int rowA = wm + i * 16 + lr;
      a_off[i][h] = rowA * 128 + ((ch ^ (rowA & 7)) << 4);
    }
#pragma unroll
    for (int j = 0; j < 4; ++j) {
      const int rowB = wn + j * 16 + lr;
      b_off[j][h] = rowB * 128 + ((ch ^ (rowB & 7)) << 4);
    }
  }

  v4f facc[4][4];
#pragma unroll
  for (int i = 0; i < 4; ++i)
#pragma unroll
    for (int j = 0; j < 4; ++j) facc[i][j] = {0.f, 0.f, 0.f, 0.f};

  const float* wsp = wscale + n0 + wn + lr;  // wscale[b*N + n], n = +j*16

  for (int kb = 0; kb < NBLK; ++kb) {
    // prefetch this block's 4 column scales above the barrier (latency slack)
    float wsv[4];
#pragma unroll
    for (int j = 0; j < 4; ++j) wsv[j] = wsp[(size_t)kb * N_DIM + j * 16];

    __syncthreads();
#pragma unroll
    for (int p = 0; p < 4; ++p) {
      gload_lds16(ga + (size_t)p * 32 * K_DIM, la_dst + p * 4096);
      gload_lds16(gb + (size_t)p * 32 * K_DIM, lb_dst + p * 4096);
    }
    ga += BLK;
    gb += BLK;
    __syncthreads();

    // all 8 A-fragments up front (32 regs); B read j-sequentially so only
    // one j-column of int accumulators (16 regs) is live at a time.
    v4i af[4][2];
#pragma unroll
    for (int i = 0; i < 4; ++i)
#pragma unroll
      for (int h = 0; h < 2; ++h) af[i][h] = *(const v4i*)(lA + a_off[i][h]);

#pragma unroll
    for (int j = 0; j < 4; ++j) {
      const v4i b0 = *(const v4i*)(lB + b_off[j][0]);
      const v4i b1 = *(const v4i*)(lB + b_off[j][1]);
      v4i ic[4];
#pragma unroll
      for (int i = 0; i < 4; ++i) {
        ic[i] = {0, 0, 0, 0};
        ic[i] = __builtin_amdgcn_mfma_i32_16x16x64_i8(af[i][0], b0, ic[i], 0, 0, 0);
        ic[i] = __builtin_amdgcn_mfma_i32_16x16x64_i8(af[i][1], b1, ic[i], 0, 0, 0);
      }
#pragma unroll
      for (int i = 0; i < 4; ++i)
#pragma unroll
        for (int r = 0; r < 4; ++r)
          facc[i][j][r] += wsv[j] * (float)ic[i][r];
    }
  }

  // epilogue: out[m,n] = facc * xs[m] + bias[n]
  float bv[4];
#pragma unroll
  for (int j = 0; j < 4; ++j) bv[j] = bias[n0 + wn + j * 16 + lr];
#pragma unroll
  for (int i = 0; i < 4; ++i) {
    const int mb = m0 + wm + i * 16 + (lq << 2);
#pragma unroll
    for (int r = 0; r < 4; ++r) {
      const float sc = xs[mb + r];
      float* op = out + (size_t)(mb + r) * N_DIM + n0 + wn + lr;
#pragma unroll
      for (int j = 0; j < 4; ++j) op[j * 16] = facc[i][j][r] * sc + bv[j];
    }
  }
}

extern "C" void kernel_launch(void* const* d_in, const int* in_sizes, int n_in,
                              void* d_out, int out_size, void* d_ws, size_t ws_size,
                              hipStream_t stream) {
  const float* x      = (const float*)d_in[0];
  const int*   w32    = (const int*)d_in[1];    // harness ABI: int8 ref -> int32 buffer
  const float* wscale = (const float*)d_in[2];
  const float* bias   = (const float*)d_in[3];
  float* out = (float*)d_out;

  // workspace layout: xq [33.5 MB] | wq8 [16.8 MB] | xs [32 KB]
  int8_t* xq  = (int8_t*)d_ws;
  int8_t* wq8 = (int8_t*)d_ws + (size_t)M_DIM * K_DIM;
  float*  xs  = (float*)((char*)d_ws + (size_t)M_DIM * K_DIM + (size_t)N_DIM * K_DIM);

  pack_w<<<(N_DIM * (size_t)K_DIM / 4 + 255) / 256, 256, 0, stream>>>(w32, (int*)wq8);
  quant_rows<<<M_DIM, 256, 0, stream>>>(x, xq, xs);
  dim3 grid(M_DIM / 128, N_DIM / 128);
  gemm_q8<<<grid, 256, 0, stream>>>(xq, wq8, wscale, xs, bias, out);
}